// Round 2
// baseline (436.570 us; speedup 1.0000x reference)
//
#include <hip/hip_runtime.h>
#include <math.h>

#define FIN   512
#define H1DIM 256
#define HEADS 4
#define CH    64
#define OUTC  40
#define NEG   0.2f
#define EPSV  1e-16f
#define BK    64

// leaky_relu(a) = max(a, 0.2a)  (valid for all a since 0 < slope < 1): mul+max
__device__ __forceinline__ float leaky(float a) { return fmaxf(a, NEG * a); }

__device__ __forceinline__ short f2bf(float f) {
    unsigned u = __builtin_bit_cast(unsigned, f);
    u += 0x7FFFu + ((u >> 16) & 1u);
    return (short)(u >> 16);
}
__device__ __forceinline__ float bf2f(short s) {
    return __builtin_bit_cast(float, ((unsigned)(unsigned short)s) << 16);
}
// packed f32->bf16 (RNE, identical rounding to f2bf): 2 elements / instruction
__device__ __forceinline__ unsigned cvtpk(float lo, float hi) {
    unsigned r;
    asm("v_cvt_pk_bf16_f32 %0, %1, %2" : "=v"(r) : "v"(lo), "v"(hi));
    return r;
}
__device__ __forceinline__ float lo16(unsigned u) {
    return __builtin_bit_cast(float, u << 16);
}
__device__ __forceinline__ float hi16(unsigned u) {
    return __builtin_bit_cast(float, u & 0xffff0000u);
}

typedef __attribute__((ext_vector_type(8))) short short8;
typedef __attribute__((ext_vector_type(4))) short short4_t;
typedef __attribute__((ext_vector_type(4))) float float4_t;

typedef unsigned int u32;
typedef const __attribute__((address_space(1))) u32 gu32;
typedef __attribute__((address_space(3))) u32 lu32;

__device__ __forceinline__ void load_lds16(const void* g, void* l) {
    __builtin_amdgcn_global_load_lds((gu32*)g, (lu32*)l, 16, 0, 0);
}

// ---------------------------------------------------------------------------
// W1 [512,256] fp32 -> w1t [256,512] bf16 (transposed)
// ---------------------------------------------------------------------------
__global__ void cvt_w1_kernel(const float* __restrict__ W1, short* __restrict__ w1t)
{
    int idx = blockIdx.x * 256 + threadIdx.x;
    if (idx >= FIN * H1DIM) return;
    int k = idx >> 8;
    int n = idx & 255;
    w1t[(size_t)n * FIN + k] = f2bf(W1[idx]);
}

// ---------------------------------------------------------------------------
// GEMM1 (MFMA bf16) + fused attention scores. A staged directly from fp32 x
// via global_load_lds; in-register cvt (v_cvt_pk_bf16_f32) at fragment read.
// ---------------------------------------------------------------------------
__global__ __launch_bounds__(256) void gemm1_mfma_kernel(
    const float* __restrict__ x, const short* __restrict__ w1t,
    const float* __restrict__ attS, const float* __restrict__ attD,
    short* __restrict__ h1b, float* __restrict__ aS1, float* __restrict__ aD1, int N)
{
    __shared__ float Alf[64 * BK];    // 16KB fp32 A-tile
    __shared__ short Bls[256 * BK];   // 32KB bf16 B-tile

    const int tid  = threadIdx.x;
    const int lane = tid & 63;
    const int wid  = tid >> 6;
    const int row0 = blockIdx.x * 64;
    const int col0 = wid * 64;
    const int quad = lane >> 4;
    const int m16  = lane & 15;

    const int achunk = ((tid & 15) ^ (tid >> 4)) * 4;
    const float* asrcA[4];
#pragma unroll
    for (int p = 0; p < 4; ++p) {
        int r = row0 + p * 16 + (tid >> 4);
        if (r >= N) r = N - 1;
        asrcA[p] = x + (size_t)r * FIN + achunk;
    }

    const int trow = tid >> 3;
    const int bswz = ((tid & 7) ^ (trow & 7)) * 8;
    const short* bsrc[8];
#pragma unroll
    for (int p = 0; p < 8; ++p)
        bsrc[p] = w1t + (size_t)(p * 32 + trow) * FIN + bswz;

    float4_t acc[4][4];
#pragma unroll
    for (int i = 0; i < 4; ++i)
#pragma unroll
        for (int j = 0; j < 4; ++j) acc[i][j] = (float4_t){0.f, 0.f, 0.f, 0.f};

    const int swzB = (m16 & 7);

    for (int k0 = 0; k0 < FIN; k0 += BK) {
#pragma unroll
        for (int p = 0; p < 4; ++p)
            load_lds16(asrcA[p] + k0, Alf + p * 1024 + tid * 4);
#pragma unroll
        for (int p = 0; p < 8; ++p)
            load_lds16(bsrc[p] + k0, Bls + p * 2048 + tid * 8);
        __syncthreads();

#pragma unroll
        for (int half = 0; half < 2; ++half) {
            short8 a[4], b[4];
#pragma unroll
            for (int i = 0; i < 4; ++i) {
                int row = i * 16 + m16;
                int c0 = (quad + 4 * half) * 2;
                float4 f0 = *(const float4*)&Alf[row * BK + ((c0 ^ m16) * 4)];
                float4 f1 = *(const float4*)&Alf[row * BK + (((c0 + 1) ^ m16) * 4)];
                unsigned* tp = (unsigned*)&a[i];
                tp[0] = cvtpk(f0.x, f0.y);
                tp[1] = cvtpk(f0.z, f0.w);
                tp[2] = cvtpk(f1.x, f1.y);
                tp[3] = cvtpk(f1.z, f1.w);
            }
#pragma unroll
            for (int j = 0; j < 4; ++j) {
                int col = col0 + j * 16 + m16;
                int sub = (quad + 4 * half) ^ swzB;
                b[j] = *(const short8*)&Bls[col * BK + sub * 8];
            }
#pragma unroll
            for (int i = 0; i < 4; ++i)
#pragma unroll
                for (int j = 0; j < 4; ++j)
                    acc[i][j] = __builtin_amdgcn_mfma_f32_16x16x32_bf16(a[i], b[j], acc[i][j], 0, 0, 0);
        }
        __syncthreads();
    }

    float attSv[4], attDv[4];
#pragma unroll
    for (int j = 0; j < 4; ++j) {
        attSv[j] = attS[col0 + j * 16 + m16];
        attDv[j] = attD[col0 + j * 16 + m16];
    }

#pragma unroll
    for (int i = 0; i < 4; ++i) {
#pragma unroll
        for (int r = 0; r < 4; ++r) {
            int row = row0 + i * 16 + quad * 4 + r;
            if (row < N) {
#pragma unroll
                for (int j = 0; j < 4; ++j)
                    h1b[(size_t)row * H1DIM + col0 + j * 16 + m16] = f2bf(acc[i][j][r]);
            }
            float ps = acc[i][0][r] * attSv[0] + acc[i][1][r] * attSv[1]
                     + acc[i][2][r] * attSv[2] + acc[i][3][r] * attSv[3];
            float pd = acc[i][0][r] * attDv[0] + acc[i][1][r] * attDv[1]
                     + acc[i][2][r] * attDv[2] + acc[i][3][r] * attDv[3];
#pragma unroll
            for (int off = 1; off < 16; off <<= 1) {
                ps += __shfl_xor(ps, off);
                pd += __shfl_xor(pd, off);
            }
            if (m16 == 0 && row < N) {
                aS1[(size_t)row * 4 + wid] = ps;
                aD1[(size_t)row * 4 + wid] = pd;
            }
        }
    }
}

// ---------------------------------------------------------------------------
// CSR build. degcount returns per-edge rank (atomic return value) so scatter
// needs no second atomic pass.
// ---------------------------------------------------------------------------
__global__ void degcount_kernel(const int* __restrict__ ei, int* __restrict__ deg,
                                int* __restrict__ rank, int E, int Etot)
{
    int e = blockIdx.x * 256 + threadIdx.x;
    if (e >= Etot) return;
    int d = (e < E) ? ei[E + e] : (e - E);
    rank[e] = atomicAdd(&deg[d], 1);
}

__global__ __launch_bounds__(1024) void scan_partial_kernel(
    const int* __restrict__ deg, int* __restrict__ offsets,
    int* __restrict__ bsums, int N)
{
    __shared__ int wsums[16];
    __shared__ int excl[16];
    int tid = threadIdx.x, lane = tid & 63, wid = tid >> 6;
    int idx = blockIdx.x * 1024 + tid;
    int v = (idx < N) ? deg[idx] : 0;
    int sv = v;
#pragma unroll
    for (int off = 1; off < 64; off <<= 1) {
        int t = __shfl_up(sv, off, 64);
        if (lane >= off) sv += t;
    }
    if (lane == 63) wsums[wid] = sv;
    __syncthreads();
    if (wid == 0 && lane < 16) {
        int wv = wsums[lane];
        int sw = wv;
#pragma unroll
        for (int off = 1; off < 16; off <<= 1) {
            int t = __shfl_up(sw, off, 64);
            if (lane >= off) sw += t;
        }
        excl[lane] = sw - wv;
        if (lane == 15) bsums[blockIdx.x] = sw;
    }
    __syncthreads();
    if (idx < N) offsets[idx + 1] = sv + excl[wid];
}

__global__ __launch_bounds__(1024) void scan_tops_kernel(
    int* __restrict__ bsums, int* __restrict__ boffs, int nb)
{
    __shared__ int wsums[16];
    __shared__ int excl[16];
    int tid = threadIdx.x, lane = tid & 63, wid = tid >> 6;
    int v = (tid < nb) ? bsums[tid] : 0;
    int sv = v;
#pragma unroll
    for (int off = 1; off < 64; off <<= 1) {
        int t = __shfl_up(sv, off, 64);
        if (lane >= off) sv += t;
    }
    if (lane == 63) wsums[wid] = sv;
    __syncthreads();
    if (wid == 0 && lane < 16) {
        int wv = wsums[lane];
        int sw = wv;
#pragma unroll
        for (int off = 1; off < 16; off <<= 1) {
            int t = __shfl_up(sw, off, 64);
            if (lane >= off) sw += t;
        }
        excl[lane] = sw - wv;
    }
    __syncthreads();
    if (tid < nb) boffs[tid] = sv + excl[wid] - v;
}

__global__ __launch_bounds__(1024) void scan_add_kernel(
    int* __restrict__ offsets, const int* __restrict__ boffs, int N)
{
    int idx = blockIdx.x * 1024 + threadIdx.x;
    if (idx == 0) offsets[0] = 0;
    if (idx < N) offsets[idx + 1] += boffs[blockIdx.x];
}

__global__ void scatter_kernel(const int* __restrict__ ei, const int* __restrict__ offsets,
                               const int* __restrict__ rank, int* __restrict__ csr_src,
                               int E, int Etot)
{
    int e = blockIdx.x * 256 + threadIdx.x;
    if (e >= Etot) return;
    int s, d;
    if (e < E) { s = ei[e]; d = ei[E + e]; }
    else       { s = e - E; d = s; }
    csr_src[offsets[d] + rank[e]] = s;
}

// ---------------------------------------------------------------------------
// agg1: fused softmax+gather. Per node, the wave preloads up to 64 CSR
// indices with ONE coalesced load, then broadcasts each src via __shfl —
// all row gathers are address-independent (deep MLP, no csr->gather chain).
// Wave split in two 32-lane halves, each handles one edge of a pair with
// short8 (16B/lane) row loads. g1b = ELU(acc/denom + b1)
// ---------------------------------------------------------------------------
__global__ __launch_bounds__(256) void agg1_kernel(
    const short* __restrict__ h1b, const float* __restrict__ aS,
    const float* __restrict__ aD, const int* __restrict__ offsets,
    const int* __restrict__ csr_src, const float* __restrict__ b1,
    short* __restrict__ g1b, int N)
{
    int lane = threadIdx.x & 63, wid = threadIdx.x >> 6;
    int half = lane >> 5;
    int l32  = lane & 31;
    int n = blockIdx.x * 4 + wid;
    if (n >= N) return;
    int start = offsets[n], end = offsets[n + 1];
    int deg = end - start;
    int h = l32 >> 3;              // head = channel/64, 8 channels per lane
    int cbase = l32 * 8;
    float adh = aD[(size_t)n * 4 + h];

    float ac[8];
#pragma unroll
    for (int c = 0; c < 8; ++c) ac[c] = 0.f;
    float denom = 0.f;

    for (int c0 = 0; c0 < deg; c0 += 64) {
        int cnt = deg - c0; if (cnt > 64) cnt = 64;
        // one coalesced load of this chunk's indices (clamped so every lane
        // holds a valid src; overshoot lanes gated by w=0 below)
        int idx = csr_src[start + c0 + (lane < cnt ? lane : cnt - 1)];
        // 8 edges per iteration: 4 pairs, each half owns one edge of a pair
        for (int e0 = 0; e0 < cnt; e0 += 8) {
#pragma unroll
            for (int q = 0; q < 4; ++q) {
                int e = e0 + 2 * q + half;
                int s = __shfl(idx, e);
                float t = aS[(size_t)s * 4 + h] + adh;
                float w = (e < cnt) ? __expf(leaky(t)) : 0.f;
                short8 r = *(const short8*)&h1b[(size_t)s * H1DIM + cbase];
                denom += w;
                const unsigned* u = (const unsigned*)&r;
#pragma unroll
                for (int k = 0; k < 4; ++k) {
                    ac[2 * k]     += w * lo16(u[k]);
                    ac[2 * k + 1] += w * hi16(u[k]);
                }
            }
        }
    }

    // combine the two half-wave partial sums
    denom += __shfl_xor(denom, 32);
#pragma unroll
    for (int c = 0; c < 8; ++c) ac[c] += __shfl_xor(ac[c], 32);

    if (half == 0) {
        float inv = 1.f / (denom + EPSV);
        float4 b0 = *(const float4*)&b1[cbase];
        float4 b4 = *(const float4*)&b1[cbase + 4];
        float v[8];
        v[0] = ac[0] * inv + b0.x;
        v[1] = ac[1] * inv + b0.y;
        v[2] = ac[2] * inv + b0.z;
        v[3] = ac[3] * inv + b0.w;
        v[4] = ac[4] * inv + b4.x;
        v[5] = ac[5] * inv + b4.y;
        v[6] = ac[6] * inv + b4.z;
        v[7] = ac[7] * inv + b4.w;
#pragma unroll
        for (int c = 0; c < 8; ++c) v[c] = v[c] > 0.f ? v[c] : expm1f(v[c]);
        short8 o;
        unsigned* op = (unsigned*)&o;
        op[0] = cvtpk(v[0], v[1]);
        op[1] = cvtpk(v[2], v[3]);
        op[2] = cvtpk(v[4], v[5]);
        op[3] = cvtpk(v[6], v[7]);
        *(short8*)&g1b[(size_t)n * H1DIM + cbase] = o;
    }
}

// ---------------------------------------------------------------------------
// GEMM2: h2b[N,40](bf16) = g1[N,256] @ W2[256,40]; fused a_src2/a_dst2
// ---------------------------------------------------------------------------
__global__ __launch_bounds__(256) void gemm2_kernel(
    const short* __restrict__ g1b, const float* __restrict__ W2,
    const float* __restrict__ attS2, const float* __restrict__ attD2,
    short* __restrict__ h2b, float* __restrict__ aS2, float* __restrict__ aD2, int N)
{
    __shared__ float rows[4][8][256];
    int lane = threadIdx.x & 63, wid = threadIdx.x >> 6;
    int nbase = blockIdx.x * 32 + wid * 8;
    bool act = lane < OUTC;
    int cc = act ? lane : 0;
    float attS = act ? attS2[lane] : 0.f;
    float attD = act ? attD2[lane] : 0.f;

#pragma unroll
    for (int i = 0; i < 8; ++i) {
        int n = nbase + i;
        float4 v = make_float4(0.f, 0.f, 0.f, 0.f);
        if (n < N) {
            short4_t hv = *(const short4_t*)&g1b[(size_t)n * H1DIM + lane * 4];
            v = make_float4(bf2f(hv[0]), bf2f(hv[1]), bf2f(hv[2]), bf2f(hv[3]));
        }
        *(float4*)&rows[wid][i][lane * 4] = v;
    }

    float acc[8];
#pragma unroll
    for (int i = 0; i < 8; ++i) acc[i] = 0.f;

    for (int k = 0; k < H1DIM; k += 4) {
        float w0 = W2[(size_t)(k + 0) * OUTC + cc];
        float w1 = W2[(size_t)(k + 1) * OUTC + cc];
        float w2 = W2[(size_t)(k + 2) * OUTC + cc];
        float w3 = W2[(size_t)(k + 3) * OUTC + cc];
#pragma unroll
        for (int i = 0; i < 8; ++i) {
            float4 g = *(const float4*)&rows[wid][i][k];
            acc[i] += g.x * w0 + g.y * w1 + g.z * w2 + g.w * w3;
        }
    }

#pragma unroll
    for (int i = 0; i < 8; ++i) {
        int n = nbase + i;
        if (n >= N) continue;   // wave-uniform
        if (act) h2b[(size_t)n * OUTC + lane] = f2bf(acc[i]);
        float ts = act ? acc[i] * attS : 0.f;
        float td = act ? acc[i] * attD : 0.f;
#pragma unroll
        for (int off = 32; off > 0; off >>= 1) {
            ts += __shfl_xor(ts, off);
            td += __shfl_xor(td, off);
        }
        if (lane == 0) { aS2[n] = ts; aD2[n] = td; }
    }
}

// ---------------------------------------------------------------------------
// agg2: fused softmax+gather (H=1) + bias + log_softmax, with the same
// index-preload + shfl broadcast (all h2b row gathers independent)
// ---------------------------------------------------------------------------
__global__ __launch_bounds__(256) void agg2_kernel(
    const short* __restrict__ h2b, const float* __restrict__ aS2,
    const float* __restrict__ aD2, const int* __restrict__ offsets,
    const int* __restrict__ csr_src, const float* __restrict__ b2,
    float* __restrict__ out, int N)
{
    int lane = threadIdx.x & 63, wid = threadIdx.x >> 6;
    int n = blockIdx.x * 4 + wid;
    if (n >= N) return;
    int start = offsets[n], end = offsets[n + 1];
    int deg = end - start;
    bool act = lane < OUTC;
    int cc = act ? lane : 0;
    float ad = aD2[n];

    float acc = 0.f, denom = 0.f;
    for (int c0 = 0; c0 < deg; c0 += 64) {
        int cnt = deg - c0; if (cnt > 64) cnt = 64;
        int idx = csr_src[start + c0 + (lane < cnt ? lane : cnt - 1)];
        for (int e0 = 0; e0 < cnt; e0 += 4) {
#pragma unroll
            for (int q = 0; q < 4; ++q) {
                int e = e0 + q;
                int s = __shfl(idx, e);
                float t = aS2[s] + ad;
                float w = (e < cnt) ? __expf(leaky(t)) : 0.f;
                short hv = h2b[(size_t)s * OUTC + cc];
                denom += w;
                acc += w * bf2f(hv);
            }
        }
    }

    float v = acc / (denom + EPSV) + (act ? b2[lane] : 0.f);

    float vm = act ? v : -INFINITY;
#pragma unroll
    for (int off = 32; off > 0; off >>= 1) vm = fmaxf(vm, __shfl_xor(vm, off));
    float ex2 = act ? __expf(v - vm) : 0.f;
    float tot = ex2;
#pragma unroll
    for (int off = 32; off > 0; off >>= 1) tot += __shfl_xor(tot, off);
    float res = v - vm - __logf(tot);
    if (act) out[(size_t)n * OUTC + lane] = res;
}

// ---------------------------------------------------------------------------
extern "C" void kernel_launch(void* const* d_in, const int* in_sizes, int n_in,
                              void* d_out, int out_size, void* d_ws, size_t ws_size,
                              hipStream_t stream)
{
    const float* x     = (const float*)d_in[0];
    const int*   ei    = (const int*)d_in[1];
    const float* W1    = (const float*)d_in[2];
    const float* attS1 = (const float*)d_in[3];
    const float* attD1 = (const float*)d_in[4];
    const float* b1    = (const float*)d_in[5];
    const float* W2    = (const float*)d_in[6];
    const float* attS2 = (const float*)d_in[7];
    const float* attD2 = (const float*)d_in[8];
    const float* b2    = (const float*)d_in[9];
    float* out = (float*)d_out;

    const int N    = in_sizes[0] / FIN;
    const int E    = in_sizes[1] / 2;
    const int Etot = E + N;
    const int nb   = (N + 1023) / 1024;

    char* ws = (char*)d_ws;
    size_t off = 0;
    auto take = [&](size_t bytes) -> char* {
        char* p = ws + off;
        off = (off + bytes + 255) & ~(size_t)255;
        return p;
    };
    short* h1b     = (short*)take((size_t)N * H1DIM * 2);
    short* g1b     = (short*)take((size_t)N * H1DIM * 2);
    short* w1t     = (short*)take((size_t)FIN * H1DIM * 2);
    float* aS1     = (float*)take((size_t)N * 4 * 4);
    float* aD1     = (float*)take((size_t)N * 4 * 4);
    short* h2b     = (short*)take((size_t)N * OUTC * 2);
    float* aS2v    = (float*)take((size_t)N * 4);
    float* aD2v    = (float*)take((size_t)N * 4);
    int*   deg     = (int*)take((size_t)N * 4);
    int*   offsets = (int*)take((size_t)(N + 1) * 4);
    int*   bsums   = (int*)take((size_t)nb * 4);
    int*   boffs   = (int*)take((size_t)nb * 4);
    int*   rank    = (int*)take((size_t)Etot * 4);
    int*   csr_src = (int*)take((size_t)Etot * 4);

    hipMemsetAsync(deg, 0, (size_t)N * 4, stream);

    cvt_w1_kernel<<<(FIN * H1DIM + 255) / 256, 256, 0, stream>>>(W1, w1t);
    gemm1_mfma_kernel<<<(N + 63) / 64, 256, 0, stream>>>(x, w1t, attS1, attD1, h1b, aS1, aD1, N);
    degcount_kernel<<<(Etot + 255) / 256, 256, 0, stream>>>(ei, deg, rank, E, Etot);
    scan_partial_kernel<<<nb, 1024, 0, stream>>>(deg, offsets, bsums, N);
    scan_tops_kernel<<<1, 1024, 0, stream>>>(bsums, boffs, nb);
    scan_add_kernel<<<nb, 1024, 0, stream>>>(offsets, boffs, N);
    scatter_kernel<<<(Etot + 255) / 256, 256, 0, stream>>>(ei, offsets, rank, csr_src, E, Etot);
    agg1_kernel<<<(N + 3) / 4, 256, 0, stream>>>(h1b, aS1, aD1, offsets, csr_src, b1, g1b, N);
    gemm2_kernel<<<(N + 31) / 32, 256, 0, stream>>>(g1b, W2, attS2, attD2, h2b, aS2v, aD2v, N);
    agg2_kernel<<<(N + 3) / 4, 256, 0, stream>>>(h2b, aS2v, aD2v, offsets, csr_src, b2, out, N);
}

// Round 4
// 389.365 us; speedup vs baseline: 1.1212x; 1.1212x over previous
//
#include <hip/hip_runtime.h>
#include <math.h>

#define FIN   512
#define H1DIM 256
#define HEADS 4
#define CH    64
#define OUTC  40
#define NEG   0.2f
#define EPSV  1e-16f
#define BK    64

// leaky_relu(a) = max(a, 0.2a)  (valid for all a since 0 < slope < 1): mul+max
__device__ __forceinline__ float leaky(float a) { return fmaxf(a, NEG * a); }

__device__ __forceinline__ short f2bf(float f) {
    unsigned u = __builtin_bit_cast(unsigned, f);
    u += 0x7FFFu + ((u >> 16) & 1u);
    return (short)(u >> 16);
}
__device__ __forceinline__ float bf2f(short s) {
    return __builtin_bit_cast(float, ((unsigned)(unsigned short)s) << 16);
}
// packed f32->bf16 (RNE): 2 elements / instruction
__device__ __forceinline__ unsigned cvtpk(float lo, float hi) {
    unsigned r;
    asm("v_cvt_pk_bf16_f32 %0, %1, %2" : "=v"(r) : "v"(lo), "v"(hi));
    return r;
}
__device__ __forceinline__ float lo16(unsigned u) {
    return __builtin_bit_cast(float, u << 16);
}
__device__ __forceinline__ float hi16(unsigned u) {
    return __builtin_bit_cast(float, u & 0xffff0000u);
}

typedef __attribute__((ext_vector_type(2))) float floatx2;

// fp8 (OCP e4m3) HW conversions. Word-select must be an immediate constant:
// template parameter keeps it a constant expression at the builtin call.
__device__ __forceinline__ unsigned f32x2_to_fp8x2(float a, float b) {
    return (unsigned)__builtin_amdgcn_cvt_pk_fp8_f32(a, b, 0, false);
}
template <bool HI>
__device__ __forceinline__ floatx2 fp8x2_to_f32(unsigned u) {
    return __builtin_amdgcn_cvt_pk_f32_fp8((int)u, HI);
}

typedef __attribute__((ext_vector_type(8))) short short8;
typedef __attribute__((ext_vector_type(4))) short short4_t;
typedef __attribute__((ext_vector_type(4))) float float4_t;

typedef unsigned int u32;
typedef const __attribute__((address_space(1))) u32 gu32;
typedef __attribute__((address_space(3))) u32 lu32;

__device__ __forceinline__ void load_lds16(const void* g, void* l) {
    __builtin_amdgcn_global_load_lds((gu32*)g, (lu32*)l, 16, 0, 0);
}

// ---------------------------------------------------------------------------
// W1 [512,256] fp32 -> w1t [256,512] bf16 (transposed)
// ---------------------------------------------------------------------------
__global__ void cvt_w1_kernel(const float* __restrict__ W1, short* __restrict__ w1t)
{
    int idx = blockIdx.x * 256 + threadIdx.x;
    if (idx >= FIN * H1DIM) return;
    int k = idx >> 8;
    int n = idx & 255;
    w1t[(size_t)n * FIN + k] = f2bf(W1[idx]);
}

// ---------------------------------------------------------------------------
// GEMM1 (MFMA bf16) + fused attention scores. A staged directly from fp32 x
// via global_load_lds; in-register cvt (v_cvt_pk_bf16_f32) at fragment read.
// h1 stored as fp8 e4m3 (only consumer is agg1's weighted mean -> bf16).
// ---------------------------------------------------------------------------
__global__ __launch_bounds__(256) void gemm1_mfma_kernel(
    const float* __restrict__ x, const short* __restrict__ w1t,
    const float* __restrict__ attS, const float* __restrict__ attD,
    unsigned char* __restrict__ h1f, float* __restrict__ aS1, float* __restrict__ aD1, int N)
{
    __shared__ float Alf[64 * BK];    // 16KB fp32 A-tile
    __shared__ short Bls[256 * BK];   // 32KB bf16 B-tile

    const int tid  = threadIdx.x;
    const int lane = tid & 63;
    const int wid  = tid >> 6;
    const int row0 = blockIdx.x * 64;
    const int col0 = wid * 64;
    const int quad = lane >> 4;
    const int m16  = lane & 15;

    const int achunk = ((tid & 15) ^ (tid >> 4)) * 4;
    const float* asrcA[4];
#pragma unroll
    for (int p = 0; p < 4; ++p) {
        int r = row0 + p * 16 + (tid >> 4);
        if (r >= N) r = N - 1;
        asrcA[p] = x + (size_t)r * FIN + achunk;
    }

    const int trow = tid >> 3;
    const int bswz = ((tid & 7) ^ (trow & 7)) * 8;
    const short* bsrc[8];
#pragma unroll
    for (int p = 0; p < 8; ++p)
        bsrc[p] = w1t + (size_t)(p * 32 + trow) * FIN + bswz;

    float4_t acc[4][4];
#pragma unroll
    for (int i = 0; i < 4; ++i)
#pragma unroll
        for (int j = 0; j < 4; ++j) acc[i][j] = (float4_t){0.f, 0.f, 0.f, 0.f};

    const int swzB = (m16 & 7);

    for (int k0 = 0; k0 < FIN; k0 += BK) {
#pragma unroll
        for (int p = 0; p < 4; ++p)
            load_lds16(asrcA[p] + k0, Alf + p * 1024 + tid * 4);
#pragma unroll
        for (int p = 0; p < 8; ++p)
            load_lds16(bsrc[p] + k0, Bls + p * 2048 + tid * 8);
        __syncthreads();

#pragma unroll
        for (int half = 0; half < 2; ++half) {
            short8 a[4], b[4];
#pragma unroll
            for (int i = 0; i < 4; ++i) {
                int row = i * 16 + m16;
                int c0 = (quad + 4 * half) * 2;
                float4 f0 = *(const float4*)&Alf[row * BK + ((c0 ^ m16) * 4)];
                float4 f1 = *(const float4*)&Alf[row * BK + (((c0 + 1) ^ m16) * 4)];
                unsigned* tp = (unsigned*)&a[i];
                tp[0] = cvtpk(f0.x, f0.y);
                tp[1] = cvtpk(f0.z, f0.w);
                tp[2] = cvtpk(f1.x, f1.y);
                tp[3] = cvtpk(f1.z, f1.w);
            }
#pragma unroll
            for (int j = 0; j < 4; ++j) {
                int col = col0 + j * 16 + m16;
                int sub = (quad + 4 * half) ^ swzB;
                b[j] = *(const short8*)&Bls[col * BK + sub * 8];
            }
#pragma unroll
            for (int i = 0; i < 4; ++i)
#pragma unroll
                for (int j = 0; j < 4; ++j)
                    acc[i][j] = __builtin_amdgcn_mfma_f32_16x16x32_bf16(a[i], b[j], acc[i][j], 0, 0, 0);
        }
        __syncthreads();
    }

    float attSv[4], attDv[4];
#pragma unroll
    for (int j = 0; j < 4; ++j) {
        attSv[j] = attS[col0 + j * 16 + m16];
        attDv[j] = attD[col0 + j * 16 + m16];
    }

#pragma unroll
    for (int i = 0; i < 4; ++i) {
#pragma unroll
        for (int r = 0; r < 4; ++r) {
            int row = row0 + i * 16 + quad * 4 + r;
            if (row < N) {
                unsigned pa = f32x2_to_fp8x2(acc[i][0][r], acc[i][1][r]);
                unsigned pb = f32x2_to_fp8x2(acc[i][2][r], acc[i][3][r]);
                unsigned char* hp = h1f + (size_t)row * H1DIM + col0 + m16;
                hp[0]  = (unsigned char)(pa & 0xff);
                hp[16] = (unsigned char)((pa >> 8) & 0xff);
                hp[32] = (unsigned char)(pb & 0xff);
                hp[48] = (unsigned char)((pb >> 8) & 0xff);
            }
            float ps = acc[i][0][r] * attSv[0] + acc[i][1][r] * attSv[1]
                     + acc[i][2][r] * attSv[2] + acc[i][3][r] * attSv[3];
            float pd = acc[i][0][r] * attDv[0] + acc[i][1][r] * attDv[1]
                     + acc[i][2][r] * attDv[2] + acc[i][3][r] * attDv[3];
#pragma unroll
            for (int off = 1; off < 16; off <<= 1) {
                ps += __shfl_xor(ps, off);
                pd += __shfl_xor(pd, off);
            }
            if (m16 == 0 && row < N) {
                aS1[(size_t)row * 4 + wid] = ps;
                aD1[(size_t)row * 4 + wid] = pd;
            }
        }
    }
}

// ---------------------------------------------------------------------------
// CSR build. degcount returns per-edge rank (atomic return value) so scatter
// needs no second atomic pass.
// ---------------------------------------------------------------------------
__global__ void degcount_kernel(const int* __restrict__ ei, int* __restrict__ deg,
                                int* __restrict__ rank, int E, int Etot)
{
    int e = blockIdx.x * 256 + threadIdx.x;
    if (e >= Etot) return;
    int d = (e < E) ? ei[E + e] : (e - E);
    rank[e] = atomicAdd(&deg[d], 1);
}

__global__ __launch_bounds__(1024) void scan_partial_kernel(
    const int* __restrict__ deg, int* __restrict__ offsets,
    int* __restrict__ bsums, int N)
{
    __shared__ int wsums[16];
    __shared__ int excl[16];
    int tid = threadIdx.x, lane = tid & 63, wid = tid >> 6;
    int idx = blockIdx.x * 1024 + tid;
    int v = (idx < N) ? deg[idx] : 0;
    int sv = v;
#pragma unroll
    for (int off = 1; off < 64; off <<= 1) {
        int t = __shfl_up(sv, off, 64);
        if (lane >= off) sv += t;
    }
    if (lane == 63) wsums[wid] = sv;
    __syncthreads();
    if (wid == 0 && lane < 16) {
        int wv = wsums[lane];
        int sw = wv;
#pragma unroll
        for (int off = 1; off < 16; off <<= 1) {
            int t = __shfl_up(sw, off, 64);
            if (lane >= off) sw += t;
        }
        excl[lane] = sw - wv;
        if (lane == 15) bsums[blockIdx.x] = sw;
    }
    __syncthreads();
    if (idx < N) offsets[idx + 1] = sv + excl[wid];
}

__global__ __launch_bounds__(1024) void scan_tops_kernel(
    int* __restrict__ bsums, int* __restrict__ boffs, int nb)
{
    __shared__ int wsums[16];
    __shared__ int excl[16];
    int tid = threadIdx.x, lane = tid & 63, wid = tid >> 6;
    int v = (tid < nb) ? bsums[tid] : 0;
    int sv = v;
#pragma unroll
    for (int off = 1; off < 64; off <<= 1) {
        int t = __shfl_up(sv, off, 64);
        if (lane >= off) sv += t;
    }
    if (lane == 63) wsums[wid] = sv;
    __syncthreads();
    if (wid == 0 && lane < 16) {
        int wv = wsums[lane];
        int sw = wv;
#pragma unroll
        for (int off = 1; off < 16; off <<= 1) {
            int t = __shfl_up(sw, off, 64);
            if (lane >= off) sw += t;
        }
        excl[lane] = sw - wv;
    }
    __syncthreads();
    if (tid < nb) boffs[tid] = sv + excl[wid] - v;
}

__global__ __launch_bounds__(1024) void scan_add_kernel(
    int* __restrict__ offsets, const int* __restrict__ boffs, int N)
{
    int idx = blockIdx.x * 1024 + threadIdx.x;
    if (idx == 0) offsets[0] = 0;
    if (idx < N) offsets[idx + 1] += boffs[blockIdx.x];
}

__global__ void scatter_kernel(const int* __restrict__ ei, const int* __restrict__ offsets,
                               const int* __restrict__ rank, int* __restrict__ csr_src,
                               int E, int Etot)
{
    int e = blockIdx.x * 256 + threadIdx.x;
    if (e >= Etot) return;
    int s, d;
    if (e < E) { s = ei[e]; d = ei[E + e]; }
    else       { s = e - E; d = s; }
    csr_src[offsets[d] + rank[e]] = s;
}

// ---------------------------------------------------------------------------
// agg1: fused softmax+gather over fp8 h1 rows (256B each). Wave split into
// two 32-lane halves, each half handles one edge of a pair with 8B/lane
// (uint2) row loads + HW fp8 decode. g1b = ELU(acc/denom + b1), bf16.
// ---------------------------------------------------------------------------
__global__ __launch_bounds__(256) void agg1_kernel(
    const unsigned char* __restrict__ h1f, const float* __restrict__ aS,
    const float* __restrict__ aD, const int* __restrict__ offsets,
    const int* __restrict__ csr_src, const float* __restrict__ b1,
    short* __restrict__ g1b, int N)
{
    int lane = threadIdx.x & 63, wid = threadIdx.x >> 6;
    int half = lane >> 5;          // which edge of the pair this lane serves
    int l32  = lane & 31;
    int n = blockIdx.x * 4 + wid;
    if (n >= N) return;
    int start = offsets[n], end = offsets[n + 1];
    int h = l32 >> 3;              // head = channel/64, 8 channels per lane
    int cbase = l32 * 8;
    float adh = aD[(size_t)n * 4 + h];

    float ac[8];
#pragma unroll
    for (int c = 0; c < 8; ++c) ac[c] = 0.f;
    float denom = 0.f;

    int p = start;
    for (; p + 4 <= end; p += 4) {
        int sA0 = csr_src[p],     sB0 = csr_src[p + 1];
        int sA1 = csr_src[p + 2], sB1 = csr_src[p + 3];
        int s0 = half ? sB0 : sA0;
        int s1 = half ? sB1 : sA1;
        float t0 = aS[(size_t)s0 * 4 + h] + adh;
        float t1 = aS[(size_t)s1 * 4 + h] + adh;
        uint2 r0 = *(const uint2*)&h1f[(size_t)s0 * H1DIM + cbase];
        uint2 r1 = *(const uint2*)&h1f[(size_t)s1 * H1DIM + cbase];
        float w0 = __expf(leaky(t0));
        float w1 = __expf(leaky(t1));
        denom += w0 + w1;
        floatx2 d0a = fp8x2_to_f32<false>(r0.x), d0b = fp8x2_to_f32<true>(r0.x);
        floatx2 d0c = fp8x2_to_f32<false>(r0.y), d0d = fp8x2_to_f32<true>(r0.y);
        floatx2 d1a = fp8x2_to_f32<false>(r1.x), d1b = fp8x2_to_f32<true>(r1.x);
        floatx2 d1c = fp8x2_to_f32<false>(r1.y), d1d = fp8x2_to_f32<true>(r1.y);
        ac[0] += w0 * d0a.x + w1 * d1a.x;
        ac[1] += w0 * d0a.y + w1 * d1a.y;
        ac[2] += w0 * d0b.x + w1 * d1b.x;
        ac[3] += w0 * d0b.y + w1 * d1b.y;
        ac[4] += w0 * d0c.x + w1 * d1c.x;
        ac[5] += w0 * d0c.y + w1 * d1c.y;
        ac[6] += w0 * d0d.x + w1 * d1d.x;
        ac[7] += w0 * d0d.y + w1 * d1d.y;
    }
    for (; p + 2 <= end; p += 2) {
        int sA = csr_src[p], sB = csr_src[p + 1];
        int s = half ? sB : sA;
        float t = aS[(size_t)s * 4 + h] + adh;
        uint2 r = *(const uint2*)&h1f[(size_t)s * H1DIM + cbase];
        float w = __expf(leaky(t));
        denom += w;
        floatx2 da = fp8x2_to_f32<false>(r.x), db = fp8x2_to_f32<true>(r.x);
        floatx2 dc = fp8x2_to_f32<false>(r.y), dd = fp8x2_to_f32<true>(r.y);
        ac[0] += w * da.x; ac[1] += w * da.y;
        ac[2] += w * db.x; ac[3] += w * db.y;
        ac[4] += w * dc.x; ac[5] += w * dc.y;
        ac[6] += w * dd.x; ac[7] += w * dd.y;
    }
    if (p < end) {   // odd tail: both halves read same edge, half 1 gated to 0
        int s = csr_src[p];
        float t = aS[(size_t)s * 4 + h] + adh;
        uint2 r = *(const uint2*)&h1f[(size_t)s * H1DIM + cbase];
        float w = half ? 0.f : __expf(leaky(t));
        denom += w;
        floatx2 da = fp8x2_to_f32<false>(r.x), db = fp8x2_to_f32<true>(r.x);
        floatx2 dc = fp8x2_to_f32<false>(r.y), dd = fp8x2_to_f32<true>(r.y);
        ac[0] += w * da.x; ac[1] += w * da.y;
        ac[2] += w * db.x; ac[3] += w * db.y;
        ac[4] += w * dc.x; ac[5] += w * dc.y;
        ac[6] += w * dd.x; ac[7] += w * dd.y;
    }

    // combine the two half-wave partial sums
    denom += __shfl_xor(denom, 32);
#pragma unroll
    for (int c = 0; c < 8; ++c) ac[c] += __shfl_xor(ac[c], 32);

    if (half == 0) {
        float inv = 1.f / (denom + EPSV);
        float4 b0 = *(const float4*)&b1[cbase];
        float4 b4 = *(const float4*)&b1[cbase + 4];
        float v[8];
        v[0] = ac[0] * inv + b0.x;
        v[1] = ac[1] * inv + b0.y;
        v[2] = ac[2] * inv + b0.z;
        v[3] = ac[3] * inv + b0.w;
        v[4] = ac[4] * inv + b4.x;
        v[5] = ac[5] * inv + b4.y;
        v[6] = ac[6] * inv + b4.z;
        v[7] = ac[7] * inv + b4.w;
#pragma unroll
        for (int c = 0; c < 8; ++c) v[c] = v[c] > 0.f ? v[c] : expm1f(v[c]);
        short8 o;
        unsigned* op = (unsigned*)&o;
        op[0] = cvtpk(v[0], v[1]);
        op[1] = cvtpk(v[2], v[3]);
        op[2] = cvtpk(v[4], v[5]);
        op[3] = cvtpk(v[6], v[7]);
        *(short8*)&g1b[(size_t)n * H1DIM + cbase] = o;
    }
}

// ---------------------------------------------------------------------------
// GEMM2: h2b[N,40](bf16) = g1[N,256] @ W2[256,40]; fused a_src2/a_dst2
// ---------------------------------------------------------------------------
__global__ __launch_bounds__(256) void gemm2_kernel(
    const short* __restrict__ g1b, const float* __restrict__ W2,
    const float* __restrict__ attS2, const float* __restrict__ attD2,
    short* __restrict__ h2b, float* __restrict__ aS2, float* __restrict__ aD2, int N)
{
    __shared__ float rows[4][8][256];
    int lane = threadIdx.x & 63, wid = threadIdx.x >> 6;
    int nbase = blockIdx.x * 32 + wid * 8;
    bool act = lane < OUTC;
    int cc = act ? lane : 0;
    float attS = act ? attS2[lane] : 0.f;
    float attD = act ? attD2[lane] : 0.f;

#pragma unroll
    for (int i = 0; i < 8; ++i) {
        int n = nbase + i;
        float4 v = make_float4(0.f, 0.f, 0.f, 0.f);
        if (n < N) {
            short4_t hv = *(const short4_t*)&g1b[(size_t)n * H1DIM + lane * 4];
            v = make_float4(bf2f(hv[0]), bf2f(hv[1]), bf2f(hv[2]), bf2f(hv[3]));
        }
        *(float4*)&rows[wid][i][lane * 4] = v;
    }

    float acc[8];
#pragma unroll
    for (int i = 0; i < 8; ++i) acc[i] = 0.f;

    for (int k = 0; k < H1DIM; k += 4) {
        float w0 = W2[(size_t)(k + 0) * OUTC + cc];
        float w1 = W2[(size_t)(k + 1) * OUTC + cc];
        float w2 = W2[(size_t)(k + 2) * OUTC + cc];
        float w3 = W2[(size_t)(k + 3) * OUTC + cc];
#pragma unroll
        for (int i = 0; i < 8; ++i) {
            float4 g = *(const float4*)&rows[wid][i][k];
            acc[i] += g.x * w0 + g.y * w1 + g.z * w2 + g.w * w3;
        }
    }

#pragma unroll
    for (int i = 0; i < 8; ++i) {
        int n = nbase + i;
        if (n >= N) continue;   // wave-uniform
        if (act) h2b[(size_t)n * OUTC + lane] = f2bf(acc[i]);
        float ts = act ? acc[i] * attS : 0.f;
        float td = act ? acc[i] * attD : 0.f;
#pragma unroll
        for (int off = 32; off > 0; off >>= 1) {
            ts += __shfl_xor(ts, off);
            td += __shfl_xor(td, off);
        }
        if (lane == 0) { aS2[n] = ts; aD2[n] = td; }
    }
}

// ---------------------------------------------------------------------------
// agg2: fused softmax+gather (H=1) + bias + log_softmax
// ---------------------------------------------------------------------------
__global__ __launch_bounds__(256) void agg2_kernel(
    const short* __restrict__ h2b, const float* __restrict__ aS2,
    const float* __restrict__ aD2, const int* __restrict__ offsets,
    const int* __restrict__ csr_src, const float* __restrict__ b2,
    float* __restrict__ out, int N)
{
    int lane = threadIdx.x & 63, wid = threadIdx.x >> 6;
    int n = blockIdx.x * 4 + wid;
    if (n >= N) return;
    int start = offsets[n], end = offsets[n + 1];
    bool act = lane < OUTC;
    int cc = act ? lane : 0;
    float ad = aD2[n];

    float acc = 0.f, denom = 0.f;
    int p = start;
    for (; p + 4 <= end; p += 4) {
        int s0 = csr_src[p], s1 = csr_src[p + 1], s2 = csr_src[p + 2], s3 = csr_src[p + 3];
        float w0 = __expf(leaky(aS2[s0] + ad));
        float w1 = __expf(leaky(aS2[s1] + ad));
        float w2 = __expf(leaky(aS2[s2] + ad));
        float w3 = __expf(leaky(aS2[s3] + ad));
        short v0 = h2b[(size_t)s0 * OUTC + cc];
        short v1 = h2b[(size_t)s1 * OUTC + cc];
        short v2 = h2b[(size_t)s2 * OUTC + cc];
        short v3 = h2b[(size_t)s3 * OUTC + cc];
        denom += w0 + w1 + w2 + w3;
        acc += w0 * bf2f(v0) + w1 * bf2f(v1) + w2 * bf2f(v2) + w3 * bf2f(v3);
    }
    for (; p < end; ++p) {
        int s = csr_src[p];
        float w = __expf(leaky(aS2[s] + ad));
        denom += w;
        acc += w * bf2f(h2b[(size_t)s * OUTC + cc]);
    }

    float v = acc / (denom + EPSV) + (act ? b2[lane] : 0.f);

    float vm = act ? v : -INFINITY;
#pragma unroll
    for (int off = 32; off > 0; off >>= 1) vm = fmaxf(vm, __shfl_xor(vm, off));
    float ex2 = act ? __expf(v - vm) : 0.f;
    float tot = ex2;
#pragma unroll
    for (int off = 32; off > 0; off >>= 1) tot += __shfl_xor(tot, off);
    float res = v - vm - __logf(tot);
    if (act) out[(size_t)n * OUTC + lane] = res;
}

// ---------------------------------------------------------------------------
extern "C" void kernel_launch(void* const* d_in, const int* in_sizes, int n_in,
                              void* d_out, int out_size, void* d_ws, size_t ws_size,
                              hipStream_t stream)
{
    const float* x     = (const float*)d_in[0];
    const int*   ei    = (const int*)d_in[1];
    const float* W1    = (const float*)d_in[2];
    const float* attS1 = (const float*)d_in[3];
    const float* attD1 = (const float*)d_in[4];
    const float* b1    = (const float*)d_in[5];
    const float* W2    = (const float*)d_in[6];
    const float* attS2 = (const float*)d_in[7];
    const float* attD2 = (const float*)d_in[8];
    const float* b2    = (const float*)d_in[9];
    float* out = (float*)d_out;

    const int N    = in_sizes[0] / FIN;
    const int E    = in_sizes[1] / 2;
    const int Etot = E + N;
    const int nb   = (N + 1023) / 1024;

    char* ws = (char*)d_ws;
    size_t off = 0;
    auto take = [&](size_t bytes) -> char* {
        char* p = ws + off;
        off = (off + bytes + 255) & ~(size_t)255;
        return p;
    };
    unsigned char* h1f = (unsigned char*)take((size_t)N * H1DIM);
    short* g1b     = (short*)take((size_t)N * H1DIM * 2);
    short* w1t     = (short*)take((size_t)FIN * H1DIM * 2);
    float* aS1     = (float*)take((size_t)N * 4 * 4);
    float* aD1     = (float*)take((size_t)N * 4 * 4);
    short* h2b     = (short*)take((size_t)N * OUTC * 2);
    float* aS2v    = (float*)take((size_t)N * 4);
    float* aD2v    = (float*)take((size_t)N * 4);
    int*   deg     = (int*)take((size_t)N * 4);
    int*   offsets = (int*)take((size_t)(N + 1) * 4);
    int*   bsums   = (int*)take((size_t)nb * 4);
    int*   boffs   = (int*)take((size_t)nb * 4);
    int*   rank    = (int*)take((size_t)Etot * 4);
    int*   csr_src = (int*)take((size_t)Etot * 4);

    (void)hipMemsetAsync(deg, 0, (size_t)N * 4, stream);

    cvt_w1_kernel<<<(FIN * H1DIM + 255) / 256, 256, 0, stream>>>(W1, w1t);
    gemm1_mfma_kernel<<<(N + 63) / 64, 256, 0, stream>>>(x, w1t, attS1, attD1, h1f, aS1, aD1, N);
    degcount_kernel<<<(Etot + 255) / 256, 256, 0, stream>>>(ei, deg, rank, E, Etot);
    scan_partial_kernel<<<nb, 1024, 0, stream>>>(deg, offsets, bsums, N);
    scan_tops_kernel<<<1, 1024, 0, stream>>>(bsums, boffs, nb);
    scan_add_kernel<<<nb, 1024, 0, stream>>>(offsets, boffs, N);
    scatter_kernel<<<(Etot + 255) / 256, 256, 0, stream>>>(ei, offsets, rank, csr_src, E, Etot);
    agg1_kernel<<<(N + 3) / 4, 256, 0, stream>>>(h1f, aS1, aD1, offsets, csr_src, b1, g1b, N);
    gemm2_kernel<<<(N + 31) / 32, 256, 0, stream>>>(g1b, W2, attS2, attD2, h2b, aS2v, aD2v, N);
    agg2_kernel<<<(N + 3) / 4, 256, 0, stream>>>(h2b, aS2v, aD2v, offsets, csr_src, b2, out, N);
}